// Round 1
// baseline (2304.312 us; speedup 1.0000x reference)
//
#include <hip/hip_runtime.h>
#include <math.h>

#define BB 64
#define DD 128
#define NN 400
#define MM 50
#define HH 8
#define KDIM 16
#define NC 4
#define KW 7

// ---------------- position encoding add: y = x + PE(d,l) ----------------
__global__ void k_add_pe(const float* __restrict__ x, float* __restrict__ y,
                         int L, int total) {
  int idx = blockIdx.x * 256 + threadIdx.x;
  if (idx >= total) return;
  int l = idx % L;
  int d = (idx / L) % DD;
  int de = d & ~1;
  float freq = expf((float)de * (-9.210340371976184f / 128.0f)); // 10000^(-de/128)
  float phase = (d & 1) ? 1.5707963267948966f : 0.0f;
  y[idx] = x[idx] + sinf((float)l * freq + phase);
}

// ---------------- LayerNorm over D (ddof=1, /(sd+eps)) ----------------
// grid: BB*nLt, block 256 = 64 l-lanes x 4 d-quarters
__global__ void k_ln(const float* __restrict__ x, float* __restrict__ y,
                     const float* __restrict__ g, const float* __restrict__ bta,
                     int L, int nLt) {
  int b = blockIdx.x / nLt;
  int lt = blockIdx.x % nLt;
  int ll = threadIdx.x & 63;
  int dq = threadIdx.x >> 6;
  int l = lt * 64 + ll;
  __shared__ float s_sum[4][64], s_sq[4][64];
  float sum = 0.f, sq = 0.f;
  const float* px = x + (size_t)b * DD * L + l;
  if (l < L) {
    for (int d = dq * 32; d < dq * 32 + 32; ++d) {
      float v = px[(size_t)d * L];
      sum += v; sq += v * v;
    }
  }
  s_sum[dq][ll] = sum; s_sq[dq][ll] = sq;
  __syncthreads();
  float ts = s_sum[0][ll] + s_sum[1][ll] + s_sum[2][ll] + s_sum[3][ll];
  float tq = s_sq[0][ll] + s_sq[1][ll] + s_sq[2][ll] + s_sq[3][ll];
  float mu = ts * (1.0f / 128.0f);
  float var = (tq - 128.0f * mu * mu) * (1.0f / 127.0f);
  float sd = sqrtf(fmaxf(var, 0.f));
  float inv = 1.0f / (sd + 1e-6f);
  if (l < L) {
    float* py = y + (size_t)b * DD * L + l;
    for (int d = dq * 32; d < dq * 32 + 32; ++d) {
      float v = px[(size_t)d * L];
      py[(size_t)d * L] = g[d] * (v - mu) * inv + bta[d];
    }
  }
}

// ---------------- depthwise conv1d K=7 pad=3 ----------------
__global__ void k_dw(const float* __restrict__ x, float* __restrict__ y,
                     const float* __restrict__ w, const float* __restrict__ bias,
                     int L, int total) {
  int idx = blockIdx.x * 256 + threadIdx.x;
  if (idx >= total) return;
  int l = idx % L;
  int d = (idx / L) % DD;
  const float* px = x + (size_t)(idx - l); // row base [b,d,:]
  float acc = bias[d];
  #pragma unroll
  for (int k = 0; k < KW; ++k) {
    int ll = l + k - 3;
    if (ll >= 0 && ll < L) acc += px[ll] * w[d * KW + k];
  }
  y[idx] = acc;
}

// ---------------- tiled [B,128,L] x W(128x128) GEMM, +bias, opt relu, residual add ----------------
// out[b,e,l] = act(sum_d x[b,d,l]*W(e,d)) + out[b,e,l];  WT: W stored [d][e] else [e][d]
// grid BB*nLt, block 256; per block: 64 l x all 128 e; 32 acc/thread.
template <bool RELU, bool WT>
__global__ void k_pw(const float* __restrict__ x, const float* __restrict__ W,
                     const float* __restrict__ bias, float* __restrict__ outb,
                     int L, int nLt) {
  int b = blockIdx.x / nLt;
  int lt = blockIdx.x % nLt;
  int l0 = lt * 64;
  __shared__ float lx[DD][64];
  int tid = threadIdx.x;
  const float* px = x + (size_t)b * DD * L;
  for (int j = 0; j < DD * 64; j += 256) {
    int idx = j + tid;
    int d = idx >> 6, l = idx & 63;
    lx[d][l] = (l0 + l < L) ? px[(size_t)d * L + l0 + l] : 0.f;
  }
  __syncthreads();
  int l = tid & 63;
  int eg = tid >> 6; // 0..3, uniform per wave
  float acc[32];
  #pragma unroll
  for (int i = 0; i < 32; ++i) acc[i] = bias[eg * 32 + i];
  for (int d = 0; d < DD; ++d) {
    float xv = lx[d][l];
    if (WT) {
      const float* pw2 = W + (size_t)d * DD + eg * 32;
      #pragma unroll
      for (int i = 0; i < 32; ++i) acc[i] += xv * pw2[i];
    } else {
      const float* pw2 = W + (size_t)(eg * 32) * DD + d;
      #pragma unroll
      for (int i = 0; i < 32; ++i) acc[i] += xv * pw2[(size_t)i * DD];
    }
  }
  if (l0 + l < L) {
    #pragma unroll
    for (int i = 0; i < 32; ++i) {
      int e = eg * 32 + i;
      size_t oi = ((size_t)b * DD + e) * L + l0 + l;
      float vl = acc[i];
      if (RELU) vl = fmaxf(vl, 0.f);
      outb[oi] = vl + outb[oi];
    }
  }
}

// ---------------- QKV projection: q/k/v [B,H,L,16] from ln-x [B,128,L] ----------------
__global__ void k_qkv(const float* __restrict__ x,
                      const float* __restrict__ Wq, const float* __restrict__ bq,
                      const float* __restrict__ Wk, const float* __restrict__ bk,
                      const float* __restrict__ Wv, const float* __restrict__ bv,
                      float* __restrict__ q, float* __restrict__ k, float* __restrict__ v,
                      int L, int total) {
  int idx = blockIdx.x * 256 + threadIdx.x;
  if (idx >= total) return;
  int kd = idx & 15;
  int l = (idx >> 4) % L;
  int h = (idx / (16 * L)) & 7;
  int b = idx / (16 * L * 8);
  const float* px = x + (size_t)b * DD * L + l;
  float aq = bq[h * KDIM + kd], ak = bk[h * KDIM + kd], av = bv[h * KDIM + kd];
  for (int d = 0; d < DD; ++d) {
    float xv = px[(size_t)d * L];
    aq += xv * Wq[((size_t)h * DD + d) * KDIM + kd];
    ak += xv * Wk[((size_t)h * DD + d) * KDIM + kd];
    av += xv * Wv[((size_t)h * DD + d) * KDIM + kd];
  }
  q[idx] = aq; k[idx] = ak; v[idx] = av;
}

// ---------------- flash attention: 1 wave per (b,h,i); o written [B,128,L] ----------------
__global__ void k_attn(const float* __restrict__ q, const float* __restrict__ k,
                       const float* __restrict__ v, const float* __restrict__ mask,
                       float* __restrict__ o, int L) {
  int bh = blockIdx.x / L; // b*8+h
  int i = blockIdx.x % L;
  int b = bh >> 3;
  int tid = threadIdx.x;
  const float* pq = q + ((size_t)bh * L + i) * KDIM;
  float qr[KDIM];
  #pragma unroll
  for (int t = 0; t < KDIM; ++t) qr[t] = pq[t];
  float m = -1e30f, ls = 0.f;
  float acc[KDIM];
  #pragma unroll
  for (int t = 0; t < KDIM; ++t) acc[t] = 0.f;
  for (int j = tid; j < L; j += 64) {
    const float* pk = k + ((size_t)bh * L + j) * KDIM;
    float s = 0.f;
    #pragma unroll
    for (int t = 0; t < KDIM; ++t) s += qr[t] * pk[t];
    s *= 0.25f; // 1/sqrt(16)
    s -= 1e30f * (1.0f - mask[b * L + j]);
    float nm = fmaxf(m, s);
    float sc = expf(m - nm);
    float p = expf(s - nm);
    ls = ls * sc + p;
    const float* pv = v + ((size_t)bh * L + j) * KDIM;
    #pragma unroll
    for (int t = 0; t < KDIM; ++t) acc[t] = acc[t] * sc + p * pv[t];
    m = nm;
  }
  float gm = m;
  #pragma unroll
  for (int off = 1; off < 64; off <<= 1) gm = fmaxf(gm, __shfl_xor(gm, off));
  float sc = expf(m - gm);
  ls *= sc;
  #pragma unroll
  for (int t = 0; t < KDIM; ++t) acc[t] *= sc;
  #pragma unroll
  for (int off = 1; off < 64; off <<= 1) {
    ls += __shfl_xor(ls, off);
    #pragma unroll
    for (int t = 0; t < KDIM; ++t) acc[t] += __shfl_xor(acc[t], off);
  }
  if (tid == 0) {
    float invl = 1.0f / ls;
    // o[b, h*16+t, i] in [B,128,L] layout
    #pragma unroll
    for (int t = 0; t < KDIM; ++t)
      o[((size_t)bh * KDIM + t) * L + i] = acc[t] * invl;
  }
}

// ---------------- [B,D,L] -> [B,L,D] transpose ----------------
__global__ void k_transpose(const float* __restrict__ X, float* __restrict__ Y,
                            int L, int total) {
  int idx = blockIdx.x * 256 + threadIdx.x;
  if (idx >= total) return;
  int d = idx % DD;
  int l = (idx / DD) % L;
  int b = idx / (DD * L);
  Y[idx] = X[((size_t)b * DD + d) * L + l];
}

// ---------------- dot over D: out[b,l] = sum_d X[b,d,l]*w[d] ----------------
__global__ void k_dotD(const float* __restrict__ X, const float* __restrict__ w,
                       float* __restrict__ out, int L, int total) {
  int idx = blockIdx.x * 256 + threadIdx.x;
  if (idx >= total) return;
  int l = idx % L;
  int b = idx / L;
  const float* px = X + (size_t)b * DD * L + l;
  float acc = 0.f;
  for (int d = 0; d < DD; ++d) acc += px[(size_t)d * L] * w[d];
  out[idx] = acc;
}

// ---------------- S[b,n,m] trilinear ----------------
__global__ void k_S(const float* __restrict__ C, const float* __restrict__ Qf,
                    const float* __restrict__ cd, const float* __restrict__ qd,
                    const float* __restrict__ wm, const float* __restrict__ bias,
                    float* __restrict__ S) {
  int idx = blockIdx.x * 256 + threadIdx.x;
  if (idx >= BB * NN * MM) return;
  int mcol = idx % MM;
  int n = (idx / MM) % NN;
  int b = idx / (MM * NN);
  const float* pc = C + (size_t)b * DD * NN + n;
  const float* pq = Qf + (size_t)b * DD * MM + mcol;
  float acc = 0.f;
  for (int d = 0; d < DD; ++d)
    acc += pc[(size_t)d * NN] * wm[d] * pq[(size_t)d * MM];
  S[idx] = acc + cd[b * NN + n] + qd[b * MM + mcol] + bias[0];
}

// ---------------- softmax over n (col) -> Sc; 1 wave per (b,m) ----------------
__global__ void k_smax_col(const float* __restrict__ S, const float* __restrict__ cmask,
                           float* __restrict__ Sc) {
  int b = blockIdx.x / MM;
  int mcol = blockIdx.x % MM;
  int tid = threadIdx.x;
  float vals[7];
  float mx = -1e30f;
  #pragma unroll
  for (int c = 0; c < 7; ++c) {
    int n = tid + c * 64;
    float s = -1e30f;
    if (n < NN)
      s = S[((size_t)b * NN + n) * MM + mcol] - 1e30f * (1.0f - cmask[b * NN + n]);
    vals[c] = s;
    mx = fmaxf(mx, s);
  }
  #pragma unroll
  for (int off = 1; off < 64; off <<= 1) mx = fmaxf(mx, __shfl_xor(mx, off));
  float sum = 0.f;
  #pragma unroll
  for (int c = 0; c < 7; ++c) { vals[c] = expf(vals[c] - mx); sum += vals[c]; }
  #pragma unroll
  for (int off = 1; off < 64; off <<= 1) sum += __shfl_xor(sum, off);
  float inv = 1.0f / sum;
  #pragma unroll
  for (int c = 0; c < 7; ++c) {
    int n = tid + c * 64;
    if (n < NN) Sc[((size_t)b * NN + n) * MM + mcol] = vals[c] * inv;
  }
}

// ---------------- softmax over m (row), in-place; 1 wave per (b,n) ----------------
__global__ void k_smax_row(float* __restrict__ S, const float* __restrict__ qmask) {
  int bn = blockIdx.x;
  int b = bn / NN;
  int tid = threadIdx.x;
  float s = -1e30f;
  if (tid < MM)
    s = S[(size_t)bn * MM + tid] - 1e30f * (1.0f - qmask[b * MM + tid]);
  float mx = s;
  #pragma unroll
  for (int off = 1; off < 64; off <<= 1) mx = fmaxf(mx, __shfl_xor(mx, off));
  float e = (tid < MM) ? expf(s - mx) : 0.f;
  float sum = e;
  #pragma unroll
  for (int off = 1; off < 64; off <<= 1) sum += __shfl_xor(sum, off);
  if (tid < MM) S[(size_t)bn * MM + tid] = e / sum;
}

// ---------------- U[b,m,d] = sum_k Sc[b,k,m]*C2[b,k,d] ----------------
__global__ void k_U(const float* __restrict__ Sc, const float* __restrict__ C2,
                    float* __restrict__ U) {
  int idx = blockIdx.x * 256 + threadIdx.x;
  if (idx >= BB * MM * DD) return;
  int d = idx % DD;
  int mcol = (idx / DD) % MM;
  int b = idx / (DD * MM);
  const float* psc = Sc + (size_t)b * NN * MM + mcol;
  const float* pc2 = C2 + (size_t)b * NN * DD + d;
  float acc = 0.f;
  for (int kk = 0; kk < NN; ++kk)
    acc += psc[(size_t)kk * MM] * pc2[(size_t)kk * DD];
  U[idx] = acc;
}

// ---------------- A[b,n,d], Bt[b,n,d] = sum_m Sr[b,n,m]*{Q2,U}[b,m,d] ----------------
__global__ void k_ABt(const float* __restrict__ Sr, const float* __restrict__ Q2,
                      const float* __restrict__ Uu, float* __restrict__ A,
                      float* __restrict__ Bt) {
  int idx = blockIdx.x * 256 + threadIdx.x;
  if (idx >= BB * NN * DD) return;
  int d = idx % DD;
  int n = (idx / DD) % NN;
  int b = idx / (DD * NN);
  const float* ps = Sr + ((size_t)b * NN + n) * MM;
  const float* pq = Q2 + (size_t)b * MM * DD + d;
  const float* pu = Uu + (size_t)b * MM * DD + d;
  float a = 0.f, bt = 0.f;
  for (int mcol = 0; mcol < MM; ++mcol) {
    float s = ps[mcol];
    a += s * pq[(size_t)mcol * DD];
    bt += s * pu[(size_t)mcol * DD];
  }
  A[idx] = a; Bt[idx] = bt;
}

// ---------------- final concat [C2, A, C2*A, C2*Bt] ----------------
__global__ void k_final(const float* __restrict__ C2, const float* __restrict__ A,
                        const float* __restrict__ Bt, float* __restrict__ out) {
  int idx = blockIdx.x * 256 + threadIdx.x;
  if (idx >= BB * NN * DD) return;
  int d = idx % DD;
  int bn = idx / DD;
  float c = C2[idx], a = A[idx], bt = Bt[idx];
  float* po = out + (size_t)bn * 512;
  po[d] = c;
  po[128 + d] = a;
  po[256 + d] = c * a;
  po[384 + d] = c * bt;
}

extern "C" void kernel_launch(void* const* d_in, const int* in_sizes, int n_in,
                              void* d_out, int out_size, void* d_ws, size_t ws_size,
                              hipStream_t stream) {
  (void)in_sizes; (void)n_in; (void)out_size; (void)ws_size;
  const float* ctx   = (const float*)d_in[0];
  const float* que   = (const float*)d_in[1];
  const float* cmask = (const float*)d_in[2];
  const float* qmask = (const float*)d_in[3];
  const float* ln_g  = (const float*)d_in[4];
  const float* ln_b  = (const float*)d_in[5];
  const float* dw_w  = (const float*)d_in[6];
  const float* dw_b  = (const float*)d_in[7];
  const float* pw_w  = (const float*)d_in[8];
  const float* pw_b  = (const float*)d_in[9];
  const float* Wq    = (const float*)d_in[10];
  const float* bq    = (const float*)d_in[11];
  const float* Wk    = (const float*)d_in[12];
  const float* bk    = (const float*)d_in[13];
  const float* Wv    = (const float*)d_in[14];
  const float* bv    = (const float*)d_in[15];
  const float* Wo    = (const float*)d_in[16];
  const float* bo    = (const float*)d_in[17];
  const float* Wfc   = (const float*)d_in[18];
  const float* bfc   = (const float*)d_in[19];
  const float* cq_wc = (const float*)d_in[20];
  const float* cq_wq = (const float*)d_in[21];
  const float* cq_wm = (const float*)d_in[22];
  const float* cq_b  = (const float*)d_in[23];
  float* out = (float*)d_out;
  float* ws = (float*)d_ws;

  const size_t SZ_C = (size_t)BB * DD * NN; // 3,276,800
  const size_t SZ_Q = (size_t)BB * DD * MM; //   409,600
  float* Cb = ws;
  float* t1 = Cb + SZ_C;
  float* t2 = t1 + SZ_C;
  float* t3 = t2 + SZ_C;
  float* t4 = t3 + SZ_C;
  float* Qb = t4 + SZ_C;
  float* S  = Qb + SZ_Q;
  float* Scb = S + (size_t)BB * NN * MM;
  float* Q2 = Scb + (size_t)BB * NN * MM;
  float* Uu = Q2 + SZ_Q;
  float* cd = Uu + SZ_Q;
  float* qd = cd + (size_t)BB * NN;
  // total ~20.2M floats = ~81 MB

  auto run_block = [&](const float* x, const float* mask, float* outb, int L) {
    int total = BB * DD * L;
    int nb = (total + 255) / 256;
    int nLt = (L + 63) / 64;
    k_add_pe<<<nb, 256, 0, stream>>>(x, outb, L, total);
    for (int i = 0; i < NC; ++i) {
      k_ln<<<BB * nLt, 256, 0, stream>>>(outb, t1, ln_g, ln_b, L, nLt);
      k_dw<<<nb, 256, 0, stream>>>(t1, t2, dw_w + (size_t)i * DD * KW,
                                   dw_b + (size_t)i * DD, L, total);
      k_pw<true, false><<<BB * nLt, 256, 0, stream>>>(
          t2, pw_w + (size_t)i * DD * DD, pw_b + (size_t)i * DD, outb, L, nLt);
    }
    // self-attention
    k_ln<<<BB * nLt, 256, 0, stream>>>(outb, t1, ln_g, ln_b, L, nLt);
    k_qkv<<<nb, 256, 0, stream>>>(t1, Wq, bq, Wk, bk, Wv, bv, t2, t3, t4, L, total);
    k_attn<<<BB * HH * L, 64, 0, stream>>>(t2, t3, t4, mask, t1, L);
    k_pw<false, true><<<BB * nLt, 256, 0, stream>>>(t1, Wo, bo, outb, L, nLt);
    // FFN
    k_ln<<<BB * nLt, 256, 0, stream>>>(outb, t1, ln_g, ln_b, L, nLt);
    k_pw<false, false><<<BB * nLt, 256, 0, stream>>>(t1, Wfc, bfc, outb, L, nLt);
  };

  run_block(ctx, cmask, Cb, NN);
  run_block(que, qmask, Qb, MM);

  // ---- context-query attention ----
  int totC = BB * NN * DD;
  int totQ = BB * MM * DD;
  k_transpose<<<(totC + 255) / 256, 256, 0, stream>>>(Cb, t1, NN, totC); // C2 in t1
  k_transpose<<<(totQ + 255) / 256, 256, 0, stream>>>(Qb, Q2, MM, totQ);
  k_dotD<<<(BB * NN + 255) / 256, 256, 0, stream>>>(Cb, cq_wc, cd, NN, BB * NN);
  k_dotD<<<(BB * MM + 255) / 256, 256, 0, stream>>>(Qb, cq_wq, qd, MM, BB * MM);
  k_S<<<(BB * NN * MM + 255) / 256, 256, 0, stream>>>(Cb, Qb, cd, qd, cq_wm, cq_b, S);
  k_smax_col<<<BB * MM, 64, 0, stream>>>(S, cmask, Scb);
  k_smax_row<<<BB * NN, 64, 0, stream>>>(S, qmask); // S now holds S_r
  k_U<<<(BB * MM * DD + 255) / 256, 256, 0, stream>>>(Scb, t1, Uu);
  k_ABt<<<(totC + 255) / 256, 256, 0, stream>>>(S, Q2, Uu, t2, t3); // A=t2, Bt=t3
  k_final<<<(totC + 255) / 256, 256, 0, stream>>>(t1, t2, t3, out);
}

// Round 2
// 1131.932 us; speedup vs baseline: 2.0357x; 2.0357x over previous
//
#include <hip/hip_runtime.h>
#include <math.h>

#define BB 64
#define DD 128
#define NN 400
#define MM 50
#define HH 8
#define KDIM 16
#define NC 4
#define KW 7

#define SZ_C (BB * DD * NN)   // 3,276,800
#define SZ_Q (BB * DD * MM)   //   409,600
#define SSTAT (BB * NN + BB * MM)  // 28,800; q stats at offset BB*NN

// ---------------- canonical weight transpose: Wcan[m][d][e] ----------------
// m 0..3: pw_w (e-major), m 4: Wo (d-major, copy), m 5: Wfc (e-major),
// m 6..8: Wq/Wk/Wv ([h][d][kd], e = h*16+kd)
__global__ void k_transposeW(const float* __restrict__ pw_w, const float* __restrict__ Wo,
                             const float* __restrict__ Wfc, const float* __restrict__ Wq,
                             const float* __restrict__ Wk, const float* __restrict__ Wv,
                             float* __restrict__ Wcan) {
  int idx = blockIdx.x * 256 + threadIdx.x;
  if (idx >= 9 * 16384) return;
  int m = idx >> 14;
  int r = idx & 16383;
  int d = r >> 7, e = r & 127;
  float v;
  if (m < 4) v = pw_w[m * 16384 + e * 128 + d];
  else if (m == 4) v = Wo[d * 128 + e];
  else if (m == 5) v = Wfc[e * 128 + d];
  else {
    const float* W = (m == 6) ? Wq : (m == 7) ? Wk : Wv;
    v = W[((e >> 4) * 128 + d) * 16 + (e & 15)];
  }
  Wcan[idx] = v;
}

// ---------------- position encoding add (both phases) ----------------
__global__ void k_pe(const float* __restrict__ xC, const float* __restrict__ xQ,
                     float* __restrict__ yC, float* __restrict__ yQ) {
  int idx = blockIdx.x * 256 + threadIdx.x;
  const float* x; float* y; int L, id2;
  if (idx < SZ_C) { x = xC; y = yC; L = NN; id2 = idx; }
  else if (idx < SZ_C + SZ_Q) { x = xQ; y = yQ; L = MM; id2 = idx - SZ_C; }
  else return;
  int l = id2 % L;
  int d = (id2 / L) % DD;
  int de = d & ~1;
  float freq = __expf((float)de * (-9.210340371976184f / 128.0f));
  float phase = (d & 1) ? 1.5707963267948966f : 0.0f;
  y[id2] = x[id2] + sinf((float)l * freq + phase);
}

// ---------------- LN stats: mu and 1/(sd+eps), ddof=1 ----------------
// blocks 0..447: ctx (b=blk/7, lt=blk%7); 448..511: q (b=blk-448)
__global__ void k_lnstats(const float* __restrict__ xC, const float* __restrict__ xQ,
                          float* __restrict__ mu, float* __restrict__ inv) {
  int blk = blockIdx.x;
  const float* x; int L, lt, b, soff;
  if (blk < 448) { b = blk / 7; lt = blk % 7; x = xC; L = NN; soff = 0; }
  else { b = blk - 448; lt = 0; x = xQ; L = MM; soff = BB * NN; }
  int ll = threadIdx.x & 63;
  int dq = threadIdx.x >> 6;
  int l = lt * 64 + ll;
  __shared__ float s_sum[4][64], s_sq[4][64];
  float sum = 0.f, sq = 0.f;
  const float* px = x + (size_t)b * DD * L + l;
  if (l < L) {
    for (int d = dq * 32; d < dq * 32 + 32; ++d) {
      float v = px[(size_t)d * L];
      sum += v; sq += v * v;
    }
  }
  s_sum[dq][ll] = sum; s_sq[dq][ll] = sq;
  __syncthreads();
  if (dq == 0 && l < L) {
    float ts = s_sum[0][ll] + s_sum[1][ll] + s_sum[2][ll] + s_sum[3][ll];
    float tq = s_sq[0][ll] + s_sq[1][ll] + s_sq[2][ll] + s_sq[3][ll];
    float m = ts * (1.0f / 128.0f);
    float var = (tq - 128.0f * m * m) * (1.0f / 127.0f);
    float sd = sqrtf(fmaxf(var, 0.f));
    mu[soff + b * L + l] = m;
    inv[soff + b * L + l] = 1.0f / (sd + 1e-6f);
  }
}

// ---------------- depthwise conv K=7 pad=3, LN fused (both phases) ----------------
__global__ void k_dw(const float* __restrict__ xC, const float* __restrict__ xQ,
                     float* __restrict__ yC, float* __restrict__ yQ,
                     const float* __restrict__ w, const float* __restrict__ bias,
                     const float* __restrict__ mu, const float* __restrict__ inv,
                     const float* __restrict__ g, const float* __restrict__ beta) {
  int idx = blockIdx.x * 256 + threadIdx.x;
  const float* x; float* y; int L, id2, soff;
  if (idx < SZ_C) { x = xC; y = yC; L = NN; id2 = idx; soff = 0; }
  else if (idx < SZ_C + SZ_Q) { x = xQ; y = yQ; L = MM; id2 = idx - SZ_C; soff = BB * NN; }
  else return;
  int l = id2 % L;
  int d = (id2 / L) % DD;
  int b = id2 / (DD * L);
  const float* px = x + (size_t)(id2 - l);
  const float* pmu = mu + soff + b * L;
  const float* pin = inv + soff + b * L;
  float gd = g[d], bd = beta[d];
  float acc = bias[d];
  #pragma unroll
  for (int k = 0; k < KW; ++k) {
    int lt = l + k - 3;
    if (lt >= 0 && lt < L) {
      float v = gd * (px[lt] - pmu[lt]) * pin[lt] + bd;
      acc += v * w[d * KW + k];
    }
  }
  y[id2] = acc;
}

// ---------------- 128x128 GEMM over [B,128,L], both phases ----------------
// out[b,e,l] (+)= act(sum_d xln[b,d,l] * Wc[d][e] + bias[e])
// LNF: apply LN with stats during X staging. ACT: 0=write, 1=+residual, 2=relu+residual
template <int LNF, int ACT>
__global__ __launch_bounds__(256) void k_gemm128(
    const float* __restrict__ xC, const float* __restrict__ xQ,
    float* __restrict__ outC, float* __restrict__ outQ,
    const float* __restrict__ Wc, const float* __restrict__ bias,
    const float* __restrict__ mu, const float* __restrict__ inv,
    const float* __restrict__ g, const float* __restrict__ beta) {
  int blk = blockIdx.x;
  int b = blk / 5, tile = blk % 5;
  const float* x; float* out; int L, l0, soff;
  if (tile < 4) { x = xC; out = outC; L = NN; l0 = tile * 128; soff = 0; }
  else { x = xQ; out = outQ; L = MM; l0 = 0; soff = BB * NN; }
  __shared__ float Wl[32 * 128];
  __shared__ float Xl[32 * 128];
  int tid = threadIdx.x;
  float acc[8][8];
  #pragma unroll
  for (int i = 0; i < 8; ++i)
    #pragma unroll
    for (int j = 0; j < 8; ++j) acc[i][j] = 0.f;
  const float* xb = x + (size_t)b * DD * L;
  const float* pmu = mu + soff + b * L;
  const float* pin = inv + soff + b * L;
  for (int kc = 0; kc < 4; ++kc) {
    int d0 = kc * 32;
    #pragma unroll
    for (int i = 0; i < 16; ++i) {
      int idx = i * 256 + tid;
      Wl[idx] = Wc[(size_t)(d0 + (idx >> 7)) * 128 + (idx & 127)];
    }
    #pragma unroll
    for (int i = 0; i < 16; ++i) {
      int idx = i * 256 + tid;
      int k = idx >> 7, l = idx & 127;
      float v = 0.f;
      if (l0 + l < L) {
        v = xb[(size_t)(d0 + k) * L + l0 + l];
        if (LNF) v = g[d0 + k] * (v - pmu[l0 + l]) * pin[l0 + l] + beta[d0 + k];
      }
      Xl[idx] = v;
    }
    __syncthreads();
    int e0 = (tid >> 4) * 8, lq = (tid & 15) * 8;
    for (int k = 0; k < 32; ++k) {
      const float4* wp = (const float4*)&Wl[k * 128 + e0];
      const float4* xp = (const float4*)&Xl[k * 128 + lq];
      float4 w0 = wp[0], w1 = wp[1], x0 = xp[0], x1 = xp[1];
      float we[8] = {w0.x, w0.y, w0.z, w0.w, w1.x, w1.y, w1.z, w1.w};
      float xe[8] = {x0.x, x0.y, x0.z, x0.w, x1.x, x1.y, x1.z, x1.w};
      #pragma unroll
      for (int i = 0; i < 8; ++i)
        #pragma unroll
        for (int j = 0; j < 8; ++j) acc[i][j] += we[i] * xe[j];
    }
    __syncthreads();
  }
  int e0 = (tid >> 4) * 8, lq = l0 + (tid & 15) * 8;
  #pragma unroll
  for (int i = 0; i < 8; ++i) {
    float bi = bias[e0 + i];
    float* po = out + ((size_t)b * DD + e0 + i) * L;
    #pragma unroll
    for (int j = 0; j < 8; ++j) {
      int l = lq + j;
      if (l < L) {
        float v = acc[i][j] + bi;
        if (ACT == 2) v = fmaxf(v, 0.f);
        if (ACT == 0) po[l] = v;
        else po[l] = v + po[l];
      }
    }
  }
}

// ---------------- attention: block per (b,h,phase); K,V,mask in LDS ----------------
// q/k/v/o are [B,128,L] planes, channel = h*16+t. Lane = query, j uniform.
__global__ __launch_bounds__(256) void k_attn2(
    const float* __restrict__ qC, const float* __restrict__ kC, const float* __restrict__ vC,
    const float* __restrict__ qQ, const float* __restrict__ kQ, const float* __restrict__ vQ,
    const float* __restrict__ cmask, const float* __restrict__ qmask,
    float* __restrict__ oC, float* __restrict__ oQ) {
  int blk = blockIdx.x;
  const float *qp, *kp, *vp, *mk; float* op; int L, b, h;
  if (blk < 512) { b = blk >> 3; h = blk & 7; qp = qC; kp = kC; vp = vC; mk = cmask; op = oC; L = NN; }
  else { int bb = blk - 512; b = bb >> 3; h = bb & 7; qp = qQ; kp = kQ; vp = vQ; mk = qmask; op = oQ; L = MM; }
  __shared__ float Kl[NN * KDIM];
  __shared__ float Vl[NN * KDIM];
  __shared__ float Ml[NN];
  int tid = threadIdx.x;
  size_t base = ((size_t)b * DD + h * KDIM) * L;
  for (int idx = tid; idx < KDIM * L; idx += 256) {
    int t = idx / L, j = idx - t * L;
    Kl[j * KDIM + t] = kp[base + (size_t)t * L + j];
    Vl[j * KDIM + t] = vp[base + (size_t)t * L + j];
  }
  for (int j = tid; j < L; j += 256) Ml[j] = mk[b * L + j];
  __syncthreads();
  for (int i0 = 0; i0 < L; i0 += 256) {
    int i = i0 + tid;
    bool act = i < L;
    float q[KDIM];
    #pragma unroll
    for (int t = 0; t < KDIM; ++t) q[t] = act ? qp[base + (size_t)t * L + i] : 0.f;
    float m = -1e30f, ls = 0.f;
    float acc[KDIM];
    #pragma unroll
    for (int t = 0; t < KDIM; ++t) acc[t] = 0.f;
    for (int j0 = 0; j0 < L; j0 += 8) {
      float s[8];
      #pragma unroll
      for (int jj = 0; jj < 8; ++jj) {
        int j = j0 + jj;
        float sv = -1e30f;
        if (j < L) {
          const float4* kf = (const float4*)&Kl[j * KDIM];
          float4 k0 = kf[0], k1 = kf[1], k2 = kf[2], k3 = kf[3];
          sv = q[0] * k0.x + q[1] * k0.y + q[2] * k0.z + q[3] * k0.w
             + q[4] * k1.x + q[5] * k1.y + q[6] * k1.z + q[7] * k1.w
             + q[8] * k2.x + q[9] * k2.y + q[10] * k2.z + q[11] * k2.w
             + q[12] * k3.x + q[13] * k3.y + q[14] * k3.z + q[15] * k3.w;
          sv = sv * 0.25f - 1e30f * (1.0f - Ml[j]);
        }
        s[jj] = sv;
      }
      float cm = s[0];
      #pragma unroll
      for (int jj = 1; jj < 8; ++jj) cm = fmaxf(cm, s[jj]);
      float nm = fmaxf(m, cm);
      float sc = __expf(m - nm);
      ls *= sc;
      #pragma unroll
      for (int t = 0; t < KDIM; ++t) acc[t] *= sc;
      #pragma unroll
      for (int jj = 0; jj < 8; ++jj) {
        int j = j0 + jj;
        if (j < L) {
          float p = __expf(s[jj] - nm);
          ls += p;
          const float4* vf = (const float4*)&Vl[j * KDIM];
          float4 v0 = vf[0], v1 = vf[1], v2 = vf[2], v3 = vf[3];
          acc[0] += p * v0.x;  acc[1] += p * v0.y;  acc[2] += p * v0.z;  acc[3] += p * v0.w;
          acc[4] += p * v1.x;  acc[5] += p * v1.y;  acc[6] += p * v1.z;  acc[7] += p * v1.w;
          acc[8] += p * v2.x;  acc[9] += p * v2.y;  acc[10] += p * v2.z; acc[11] += p * v2.w;
          acc[12] += p * v3.x; acc[13] += p * v3.y; acc[14] += p * v3.z; acc[15] += p * v3.w;
        }
      }
      m = nm;
    }
    if (act) {
      float invl = 1.0f / ls;
      #pragma unroll
      for (int t = 0; t < KDIM; ++t)
        op[base + (size_t)t * L + i] = acc[t] * invl;
    }
  }
}

// ---------------- [B,D,L] -> [B,L,D] transpose ----------------
__global__ void k_transpose(const float* __restrict__ X, float* __restrict__ Y,
                            int L, int total) {
  int idx = blockIdx.x * 256 + threadIdx.x;
  if (idx >= total) return;
  int d = idx % DD;
  int l = (idx / DD) % L;
  int b = idx / (DD * L);
  Y[idx] = X[((size_t)b * DD + d) * L + l];
}

// ---------------- dot over D: out[b,l] = sum_d X[b,d,l]*w[d] ----------------
__global__ void k_dotD(const float* __restrict__ X, const float* __restrict__ w,
                       float* __restrict__ out, int L, int total) {
  int idx = blockIdx.x * 256 + threadIdx.x;
  if (idx >= total) return;
  int l = idx % L;
  int b = idx / L;
  const float* px = X + (size_t)b * DD * L + l;
  float acc = 0.f;
  for (int d = 0; d < DD; ++d) acc += px[(size_t)d * L] * w[d];
  out[idx] = acc;
}

// ---------------- S[b,n,m] trilinear ----------------
__global__ void k_S(const float* __restrict__ C, const float* __restrict__ Qf,
                    const float* __restrict__ cd, const float* __restrict__ qd,
                    const float* __restrict__ wm, const float* __restrict__ bias,
                    float* __restrict__ S) {
  int idx = blockIdx.x * 256 + threadIdx.x;
  if (idx >= BB * NN * MM) return;
  int mcol = idx % MM;
  int n = (idx / MM) % NN;
  int b = idx / (MM * NN);
  const float* pc = C + (size_t)b * DD * NN + n;
  const float* pq = Qf + (size_t)b * DD * MM + mcol;
  float acc = 0.f;
  for (int d = 0; d < DD; ++d)
    acc += pc[(size_t)d * NN] * wm[d] * pq[(size_t)d * MM];
  S[idx] = acc + cd[b * NN + n] + qd[b * MM + mcol] + bias[0];
}

// ---------------- softmax over n (col) -> Sc; 1 wave per (b,m) ----------------
__global__ void k_smax_col(const float* __restrict__ S, const float* __restrict__ cmask,
                           float* __restrict__ Sc) {
  int b = blockIdx.x / MM;
  int mcol = blockIdx.x % MM;
  int tid = threadIdx.x;
  float vals[7];
  float mx = -1e30f;
  #pragma unroll
  for (int c = 0; c < 7; ++c) {
    int n = tid + c * 64;
    float s = -1e30f;
    if (n < NN)
      s = S[((size_t)b * NN + n) * MM + mcol] - 1e30f * (1.0f - cmask[b * NN + n]);
    vals[c] = s;
    mx = fmaxf(mx, s);
  }
  #pragma unroll
  for (int off = 1; off < 64; off <<= 1) mx = fmaxf(mx, __shfl_xor(mx, off));
  float sum = 0.f;
  #pragma unroll
  for (int c = 0; c < 7; ++c) { vals[c] = __expf(vals[c] - mx); sum += vals[c]; }
  #pragma unroll
  for (int off = 1; off < 64; off <<= 1) sum += __shfl_xor(sum, off);
  float inv = 1.0f / sum;
  #pragma unroll
  for (int c = 0; c < 7; ++c) {
    int n = tid + c * 64;
    if (n < NN) Sc[((size_t)b * NN + n) * MM + mcol] = vals[c] * inv;
  }
}

// ---------------- softmax over m (row), in-place; 1 wave per (b,n) ----------------
__global__ void k_smax_row(float* __restrict__ S, const float* __restrict__ qmask) {
  int bn = blockIdx.x;
  int b = bn / NN;
  int tid = threadIdx.x;
  float s = -1e30f;
  if (tid < MM)
    s = S[(size_t)bn * MM + tid] - 1e30f * (1.0f - qmask[b * MM + tid]);
  float mx = s;
  #pragma unroll
  for (int off = 1; off < 64; off <<= 1) mx = fmaxf(mx, __shfl_xor(mx, off));
  float e = (tid < MM) ? __expf(s - mx) : 0.f;
  float sum = e;
  #pragma unroll
  for (int off = 1; off < 64; off <<= 1) sum += __shfl_xor(sum, off);
  if (tid < MM) S[(size_t)bn * MM + tid] = e / sum;
}

// ---------------- U[b,m,d] = sum_k Sc[b,k,m]*C2[b,k,d] ----------------
__global__ void k_U(const float* __restrict__ Sc, const float* __restrict__ C2,
                    float* __restrict__ U) {
  int idx = blockIdx.x * 256 + threadIdx.x;
  if (idx >= BB * MM * DD) return;
  int d = idx % DD;
  int mcol = (idx / DD) % MM;
  int b = idx / (DD * MM);
  const float* psc = Sc + (size_t)b * NN * MM + mcol;
  const float* pc2 = C2 + (size_t)b * NN * DD + d;
  float acc = 0.f;
  for (int kk = 0; kk < NN; ++kk)
    acc += psc[(size_t)kk * MM] * pc2[(size_t)kk * DD];
  U[idx] = acc;
}

// ---------------- A, Bt = Sr @ {Q2, U} ----------------
__global__ void k_ABt(const float* __restrict__ Sr, const float* __restrict__ Q2,
                      const float* __restrict__ Uu, float* __restrict__ A,
                      float* __restrict__ Bt) {
  int idx = blockIdx.x * 256 + threadIdx.x;
  if (idx >= BB * NN * DD) return;
  int d = idx % DD;
  int n = (idx / DD) % NN;
  int b = idx / (DD * NN);
  const float* ps = Sr + ((size_t)b * NN + n) * MM;
  const float* pq = Q2 + (size_t)b * MM * DD + d;
  const float* pu = Uu + (size_t)b * MM * DD + d;
  float a = 0.f, bt = 0.f;
  for (int mcol = 0; mcol < MM; ++mcol) {
    float s = ps[mcol];
    a += s * pq[(size_t)mcol * DD];
    bt += s * pu[(size_t)mcol * DD];
  }
  A[idx] = a; Bt[idx] = bt;
}

// ---------------- final concat [C2, A, C2*A, C2*Bt] ----------------
__global__ void k_final(const float* __restrict__ C2, const float* __restrict__ A,
                        const float* __restrict__ Bt, float* __restrict__ out) {
  int idx = blockIdx.x * 256 + threadIdx.x;
  if (idx >= BB * NN * DD) return;
  int d = idx % DD;
  int bn = idx / DD;
  float c = C2[idx], a = A[idx], bt = Bt[idx];
  float* po = out + (size_t)bn * 512;
  po[d] = c;
  po[128 + d] = a;
  po[256 + d] = c * a;
  po[384 + d] = c * bt;
}

extern "C" void kernel_launch(void* const* d_in, const int* in_sizes, int n_in,
                              void* d_out, int out_size, void* d_ws, size_t ws_size,
                              hipStream_t stream) {
  (void)in_sizes; (void)n_in; (void)out_size; (void)ws_size;
  const float* ctx   = (const float*)d_in[0];
  const float* que   = (const float*)d_in[1];
  const float* cmask = (const float*)d_in[2];
  const float* qmask = (const float*)d_in[3];
  const float* ln_g  = (const float*)d_in[4];
  const float* ln_b  = (const float*)d_in[5];
  const float* dw_w  = (const float*)d_in[6];
  const float* dw_b  = (const float*)d_in[7];
  const float* pw_w  = (const float*)d_in[8];
  const float* pw_b  = (const float*)d_in[9];
  const float* Wq    = (const float*)d_in[10];
  const float* bq    = (const float*)d_in[11];
  const float* Wk    = (const float*)d_in[12];
  const float* bk    = (const float*)d_in[13];
  const float* Wv    = (const float*)d_in[14];
  const float* bv    = (const float*)d_in[15];
  const float* Wo    = (const float*)d_in[16];
  const float* bo    = (const float*)d_in[17];
  const float* Wfc   = (const float*)d_in[18];
  const float* bfc   = (const float*)d_in[19];
  const float* cq_wc = (const float*)d_in[20];
  const float* cq_wq = (const float*)d_in[21];
  const float* cq_wm = (const float*)d_in[22];
  const float* cq_b  = (const float*)d_in[23];
  float* out = (float*)d_out;
  float* ws = (float*)d_ws;

  float* Cb   = ws;
  float* Qb   = Cb + SZ_C;
  float* t1C  = Qb + SZ_Q;
  float* t1Q  = t1C + SZ_C;
  float* t2C  = t1Q + SZ_Q;
  float* t2Q  = t2C + SZ_C;
  float* t3C  = t2Q + SZ_Q;
  float* t3Q  = t3C + SZ_C;
  float* t4C  = t3Q + SZ_Q;
  float* t4Q  = t4C + SZ_C;
  float* muB  = t4Q + SZ_Q;
  float* invB = muB + SSTAT;
  float* Wcan = invB + SSTAT;
  // Wcan: 9*16384 floats; total ws usage ~74.5 MB

  int totAll = SZ_C + SZ_Q;
  int nbAll = (totAll + 255) / 256;

  k_transposeW<<<(9 * 16384 + 255) / 256, 256, 0, stream>>>(pw_w, Wo, Wfc, Wq, Wk, Wv, Wcan);
  k_pe<<<nbAll, 256, 0, stream>>>(ctx, que, Cb, Qb);

  for (int i = 0; i < NC; ++i) {
    k_lnstats<<<512, 256, 0, stream>>>(Cb, Qb, muB, invB);
    k_dw<<<nbAll, 256, 0, stream>>>(Cb, Qb, t1C, t1Q,
                                    dw_w + (size_t)i * DD * KW, dw_b + (size_t)i * DD,
                                    muB, invB, ln_g, ln_b);
    k_gemm128<0, 2><<<320, 256, 0, stream>>>(t1C, t1Q, Cb, Qb,
                                             Wcan + (size_t)i * 16384, pw_b + (size_t)i * DD,
                                             muB, invB, ln_g, ln_b);
  }
  // self-attention
  k_lnstats<<<512, 256, 0, stream>>>(Cb, Qb, muB, invB);
  k_gemm128<1, 0><<<320, 256, 0, stream>>>(Cb, Qb, t1C, t1Q, Wcan + 6 * 16384, bq,
                                           muB, invB, ln_g, ln_b);
  k_gemm128<1, 0><<<320, 256, 0, stream>>>(Cb, Qb, t2C, t2Q, Wcan + 7 * 16384, bk,
                                           muB, invB, ln_g, ln_b);
  k_gemm128<1, 0><<<320, 256, 0, stream>>>(Cb, Qb, t3C, t3Q, Wcan + 8 * 16384, bv,
                                           muB, invB, ln_g, ln_b);
  k_attn2<<<1024, 256, 0, stream>>>(t1C, t2C, t3C, t1Q, t2Q, t3Q, cmask, qmask, t4C, t4Q);
  k_gemm128<0, 1><<<320, 256, 0, stream>>>(t4C, t4Q, Cb, Qb, Wcan + 4 * 16384, bo,
                                           muB, invB, ln_g, ln_b);
  // FFN (in-place residual: each block reads its full x-region before writing)
  k_lnstats<<<512, 256, 0, stream>>>(Cb, Qb, muB, invB);
  k_gemm128<1, 1><<<320, 256, 0, stream>>>(Cb, Qb, Cb, Qb, Wcan + 5 * 16384, bfc,
                                           muB, invB, ln_g, ln_b);

  // ---- context-query attention ----
  float* C2  = t1C;
  float* Q2  = t1Q;
  float* S   = t2C;
  float* Scb = t3C;
  float* Uu  = t2Q;
  float* cd  = t3Q;
  float* qd  = t4Q;
  float* A   = t4C;
  float* Bt  = Cb;  // Cb free after its readers below

  int totC = BB * NN * DD;
  int totQ = BB * MM * DD;
  k_transpose<<<(totC + 255) / 256, 256, 0, stream>>>(Cb, C2, NN, totC);
  k_transpose<<<(totQ + 255) / 256, 256, 0, stream>>>(Qb, Q2, MM, totQ);
  k_dotD<<<(BB * NN + 255) / 256, 256, 0, stream>>>(Cb, cq_wc, cd, NN, BB * NN);
  k_dotD<<<(BB * MM + 255) / 256, 256, 0, stream>>>(Qb, cq_wq, qd, MM, BB * MM);
  k_S<<<(BB * NN * MM + 255) / 256, 256, 0, stream>>>(Cb, Qb, cd, qd, cq_wm, cq_b, S);
  k_smax_col<<<BB * MM, 64, 0, stream>>>(S, cmask, Scb);
  k_smax_row<<<BB * NN, 64, 0, stream>>>(S, qmask); // S now holds S_r
  k_U<<<(BB * MM * DD + 255) / 256, 256, 0, stream>>>(Scb, C2, Uu);
  k_ABt<<<(totC + 255) / 256, 256, 0, stream>>>(S, Q2, Uu, A, Bt);
  k_final<<<(totC + 255) / 256, 256, 0, stream>>>(C2, A, Bt, out);
}